// Round 15
// baseline (257.641 us; speedup 1.0000x reference)
//
#include <hip/hip_runtime.h>
#include <hip/hip_cooperative_groups.h>

namespace cg = cooperative_groups;

#define NCLS 512
#define DIM 512
#define D4 128            // float4 per row
#define CAP 512           // slots per class (max count ~185; big margin)
#define NBLK 512
#define NTHR 512
#define EPS 1e-6f
#define MARGIN 1.0f

typedef float f32x4 __attribute__((ext_vector_type(4)));

// One cooperative kernel, 5 phases separated by grid.sync().
// 512 blocks x 512 thr, (512,4): <=128 VGPR, 10.3 KB LDS -> 2 blocks/CU,
// all 512 blocks co-resident (requirement for cooperative launch).
__global__ __launch_bounds__(NTHR, 4)
void k_fused(const f32x4* __restrict__ x4, const int* __restrict__ lab,
             int* __restrict__ cur, int* __restrict__ slots,
             f32x4* __restrict__ cls_sums4, float* __restrict__ total,
             float* __restrict__ d_out, int N)
{
    cg::grid_group grid = cg::this_grid();
    const int b  = blockIdx.x;
    const int t  = threadIdx.x;
    const int gt = b * NTHR + t;

    __shared__ int   s_idx[CAP];
    __shared__ f32x4 s_red[NTHR];
    __shared__ float s_f[8];

    // ---- phase 0: zero cur/total/d_out ----
    if (gt < NCLS) { cur[gt] = 0; total[gt] = 0.f; }
    if (gt == 0) d_out[0] = 0.f;
    grid.sync();

    // ---- phase 1: scatter sample indices into per-class slot lists ----
    if (gt < N) {
        const int c = lab[gt];
        const int p = atomicAdd(&cur[c], 1);
        if (p < CAP) slots[c * CAP + p] = gt;
    }
    grid.sync();

    // ---- phase 2: per-class gather-sum (block = class), 8 loads in flight ----
    {
        const int c    = b;
        const int col4 = t & 127;
        const int rq   = t >> 7;     // 0..3
        int m = cur[c];
        if (m > CAP) m = CAP;

        for (int k = t; k < m; k += NTHR) s_idx[k] = slots[c * CAP + k];
        __syncthreads();

        f32x4 acc = (f32x4)(0.f);

        int base = 0;
        for (; base + 32 <= m; base += 32) {
            const int i0 = s_idx[base      + rq];
            const int i1 = s_idx[base +  4 + rq];
            const int i2 = s_idx[base +  8 + rq];
            const int i3 = s_idx[base + 12 + rq];
            const int i4 = s_idx[base + 16 + rq];
            const int i5 = s_idx[base + 20 + rq];
            const int i6 = s_idx[base + 24 + rq];
            const int i7 = s_idx[base + 28 + rq];
            f32x4 v0 = x4[(size_t)i0 * D4 + col4];
            f32x4 v1 = x4[(size_t)i1 * D4 + col4];
            f32x4 v2 = x4[(size_t)i2 * D4 + col4];
            f32x4 v3 = x4[(size_t)i3 * D4 + col4];
            f32x4 v4 = x4[(size_t)i4 * D4 + col4];
            f32x4 v5 = x4[(size_t)i5 * D4 + col4];
            f32x4 v6 = x4[(size_t)i6 * D4 + col4];
            f32x4 v7 = x4[(size_t)i7 * D4 + col4];
            // Register pin: force all 8 float4 loads simultaneously live so the
            // allocator cannot serialize them (R9/R12/R14: VGPR=32 -> 1.6 TB/s).
            asm volatile("" : "+v"(v0), "+v"(v1), "+v"(v2), "+v"(v3),
                              "+v"(v4), "+v"(v5), "+v"(v6), "+v"(v7));
            acc += ((v0 + v1) + (v2 + v3)) + ((v4 + v5) + (v6 + v7));
        }
        for (; base + 4 <= m; base += 4) {
            const int i0 = s_idx[base + rq];
            acc += x4[(size_t)i0 * D4 + col4];
        }
        if (base + rq < m) {
            const int i0 = s_idx[base + rq];
            acc += x4[(size_t)i0 * D4 + col4];
        }

        s_red[t] = acc;
        __syncthreads();
        if (t < 128) {
            const f32x4 s = ((s_red[t] + s_red[t + 128]) + (s_red[t + 256] + s_red[t + 384]));
            cls_sums4[(size_t)c * D4 + t] = s;
        }
    }
    grid.sync();

    // ---- phase 3: total[d] = sum_c cls_sums[c][d]  (blocks 0..3) ----
    if (b < 4) {
        const int col4 = b * 32 + (t & 31);
        const int grp  = t >> 5;   // 0..15, each sums 32 classes
        f32x4 s = (f32x4)(0.f);
        for (int c = grp * 32; c < grp * 32 + 32; ++c)
            s += cls_sums4[(size_t)c * D4 + col4];
        s_red[t] = s;
        __syncthreads();
        if (t < 32) {
            f32x4 a = s_red[t];
            #pragma unroll
            for (int k = 1; k < 16; ++k) a += s_red[t + 32 * k];
            ((f32x4*)total)[col4] = a;
        }
    }
    grid.sync();

    // ---- phase 4: per-class hinge, accumulate loss (block = class) ----
    {
        const int c   = b;
        const int cnt = cur[c];
        const float sv = ((const float*)cls_sums4)[(size_t)c * DIM + t];
        const float tv = total[t];

        float ss = 0.f;
        if (cnt > 0) {
            const float inv_c  = 1.f / (float)cnt;
            const float inv_nc = 1.f / (float)(N - cnt);
            const float dd = sv * inv_c - (tv - sv) * inv_nc + EPS;
            ss = dd * dd;
        }
        #pragma unroll
        for (int o = 1; o < 64; o <<= 1) ss += __shfl_xor(ss, o, 64);
        if ((t & 63) == 0) s_f[t >> 6] = ss;
        __syncthreads();
        if (t == 0) {
            float tot = 0.f;
            #pragma unroll
            for (int k = 0; k < 8; ++k) tot += s_f[k];
            const float dq = sqrtf(tot);
            const float w  = fmaxf(MARGIN - dq, 0.f);
            if (cnt > 0) atomicAdd(d_out, (float)cnt * w * w / (float)N);
        }
    }
}

extern "C" void kernel_launch(void* const* d_in, const int* in_sizes, int n_in,
                              void* d_out, int out_size, void* d_ws, size_t ws_size,
                              hipStream_t stream)
{
    const f32x4* x4  = (const f32x4*)d_in[0];
    const int*   lab = (const int*)d_in[1];
    float*       out = (float*)d_out;

    int N = in_sizes[1];  // 65536 samples

    // ws layout: cur[512] | total[512] | slots[512*CAP] | cls_sums[512*512]
    int*   cur      = (int*)d_ws;
    float* total    = (float*)(cur + NCLS);
    int*   slots    = (int*)(total + NCLS);
    f32x4* cls4     = (f32x4*)(slots + (size_t)NCLS * CAP);

    void* args[] = { (void*)&x4, (void*)&lab, (void*)&cur, (void*)&slots,
                     (void*)&cls4, (void*)&total, (void*)&out, (void*)&N };
    hipLaunchCooperativeKernel((const void*)k_fused, dim3(NBLK), dim3(NTHR),
                               args, 0, stream);
}

// Round 16
// 67.946 us; speedup vs baseline: 3.7919x; 3.7919x over previous
//
#include <hip/hip_runtime.h>

#define NCLS 512
#define DIM 512
#define D4 128            // float4 per row
#define CAP 512           // slots per class (max count ~170; 512 = huge margin)
#define EPS 1e-6f
#define MARGIN 1.0f

typedef float f32x4 __attribute__((ext_vector_type(4)));

// ---------- Kernel 0: zero cur/total/d_out ----------
__global__ __launch_bounds__(512)
void k_zero(int* __restrict__ cur, float* __restrict__ total, float* __restrict__ d_out)
{
    const int t = threadIdx.x;
    cur[t] = 0;
    total[t] = 0.f;
    if (t == 0) d_out[0] = 0.f;
}

// ---------- Kernel 1: scatter sample indices into per-class slot lists ----------
__global__ __launch_bounds__(256)
void k_scatter(const int* __restrict__ lab, int* __restrict__ cur,
               int* __restrict__ slots, int N)
{
    const int i = blockIdx.x * 256 + threadIdx.x;
    if (i < N) {
        const int c = lab[i];
        const int p = atomicAdd(&cur[c], 1);
        if (p < CAP) slots[c * CAP + p] = i;
    }
}

// ---------- Kernel 2: per-class gather-sum, 8 loads in flight ----------
// __launch_bounds__(512, 4): allow up to ~128 VGPR (4 waves/SIMD -> 2 blocks/CU)
// so the 8 float4 loads genuinely stay in flight. R9/R10 post-mortem: at
// VGPR=20..32 the allocator serialized the loads -> 1.5 TB/s; this is the lever.
// NOTE (R14): do NOT fuse total[] atomics into this epilogue — doing so
// perturbs regalloc to VGPR=32 and serializes the loads (3/3 occurrences).
__global__ __launch_bounds__(512, 4)
void k_gather(const f32x4* __restrict__ x4, const int* __restrict__ slots,
              const int* __restrict__ cur, f32x4* __restrict__ cls_sums4)
{
    const int c    = blockIdx.x;
    const int t    = threadIdx.x;
    const int col4 = t & 127;
    const int rq   = t >> 7;     // 0..3
    int m = cur[c];
    if (m > CAP) m = CAP;

    __shared__ int   s_idx[CAP];
    __shared__ f32x4 s_red[512];

    for (int k = t; k < m; k += 512) s_idx[k] = slots[c * CAP + k];
    __syncthreads();

    f32x4 acc = (f32x4)(0.f);

    int base = 0;
    for (; base + 32 <= m; base += 32) {
        const int i0 = s_idx[base      + rq];
        const int i1 = s_idx[base +  4 + rq];
        const int i2 = s_idx[base +  8 + rq];
        const int i3 = s_idx[base + 12 + rq];
        const int i4 = s_idx[base + 16 + rq];
        const int i5 = s_idx[base + 20 + rq];
        const int i6 = s_idx[base + 24 + rq];
        const int i7 = s_idx[base + 28 + rq];
        const f32x4 v0 = x4[(size_t)i0 * D4 + col4];
        const f32x4 v1 = x4[(size_t)i1 * D4 + col4];
        const f32x4 v2 = x4[(size_t)i2 * D4 + col4];
        const f32x4 v3 = x4[(size_t)i3 * D4 + col4];
        const f32x4 v4 = x4[(size_t)i4 * D4 + col4];
        const f32x4 v5 = x4[(size_t)i5 * D4 + col4];
        const f32x4 v6 = x4[(size_t)i6 * D4 + col4];
        const f32x4 v7 = x4[(size_t)i7 * D4 + col4];
        acc += ((v0 + v1) + (v2 + v3)) + ((v4 + v5) + (v6 + v7));
    }
    for (; base + 4 <= m; base += 4) {
        const int i0 = s_idx[base + rq];
        acc += x4[(size_t)i0 * D4 + col4];
    }
    if (base + rq < m) {
        const int i0 = s_idx[base + rq];
        acc += x4[(size_t)i0 * D4 + col4];
    }

    s_red[t] = acc;
    __syncthreads();
    if (t < 128) {
        const f32x4 s = ((s_red[t] + s_red[t + 128]) + (s_red[t + 256] + s_red[t + 384]));
        cls_sums4[(size_t)c * D4 + t] = s;
    }
}

// ---------- Kernel 3: total[d] = sum_c cls_sums[c][d] ----------
__global__ __launch_bounds__(128)
void k_total(const f32x4* __restrict__ cls_sums4, f32x4* __restrict__ total4)
{
    const int col4 = blockIdx.x * 32 + (threadIdx.x & 31);
    const int cg   = threadIdx.x >> 5;   // 0..3, each sums 128 classes
    f32x4 s = (f32x4)(0.f);
    for (int c = cg * 128; c < cg * 128 + 128; c += 4) {
        const f32x4 a = cls_sums4[(size_t)(c + 0) * D4 + col4];
        const f32x4 b = cls_sums4[(size_t)(c + 1) * D4 + col4];
        const f32x4 d = cls_sums4[(size_t)(c + 2) * D4 + col4];
        const f32x4 e = cls_sums4[(size_t)(c + 3) * D4 + col4];
        s += (a + b) + (d + e);
    }
    __shared__ f32x4 red[128];
    red[threadIdx.x] = s;
    __syncthreads();
    if (threadIdx.x < 32) {
        const f32x4 a = (red[threadIdx.x] + red[threadIdx.x + 32])
                      + (red[threadIdx.x + 64] + red[threadIdx.x + 96]);
        total4[col4] = a;
    }
}

// ---------- Kernel 4: per-class hinge, accumulate loss ----------
__global__ __launch_bounds__(256)
void k_finalize(const float* __restrict__ cls_sums, const int* __restrict__ cnts,
                const float* __restrict__ total, float* __restrict__ d_out, int N)
{
    const int c   = blockIdx.x;
    const int tid = threadIdx.x;
    const int cnt = cnts[c];

    const float2 s = ((const float2*)cls_sums)[c * (DIM / 2) + tid];
    const float2 t = ((const float2*)total)[tid];

    float ss = 0.f;
    if (cnt > 0) {
        const float inv_c  = 1.f / (float)cnt;
        const float inv_nc = 1.f / (float)(N - cnt);
        const float d0 = s.x * inv_c - (t.x - s.x) * inv_nc + EPS;
        const float d1 = s.y * inv_c - (t.y - s.y) * inv_nc + EPS;
        ss = d0 * d0 + d1 * d1;
    }

    #pragma unroll
    for (int o = 1; o < 64; o <<= 1) ss += __shfl_xor(ss, o, 64);

    __shared__ float s_red[4];
    if ((tid & 63) == 0) s_red[tid >> 6] = ss;
    __syncthreads();

    if (tid == 0) {
        const float tot = (s_red[0] + s_red[1]) + (s_red[2] + s_red[3]);
        const float d = sqrtf(tot);
        const float w = fmaxf(MARGIN - d, 0.f);
        if (cnt > 0) atomicAdd(d_out, (float)cnt * w * w / (float)N);
    }
}

extern "C" void kernel_launch(void* const* d_in, const int* in_sizes, int n_in,
                              void* d_out, int out_size, void* d_ws, size_t ws_size,
                              hipStream_t stream)
{
    const float* x   = (const float*)d_in[0];
    const int*   lab = (const int*)d_in[1];
    float*       out = (float*)d_out;

    const int N = in_sizes[1];  // 65536 samples

    // ws layout: cur[512] | total[512] | slots[512*CAP] | cls_sums[512*512]
    int*   cur      = (int*)d_ws;
    float* total    = (float*)(cur + NCLS);
    int*   slots    = (int*)(total + NCLS);
    float* cls_sums = (float*)(slots + (size_t)NCLS * CAP);

    k_zero    <<<1, 512, 0, stream>>>(cur, total, out);
    k_scatter <<<(N + 255) / 256, 256, 0, stream>>>(lab, cur, slots, N);
    k_gather  <<<NCLS, 512, 0, stream>>>((const f32x4*)x, slots, cur,
                                         (f32x4*)cls_sums);
    k_total   <<<4, 128, 0, stream>>>((const f32x4*)cls_sums, (f32x4*)total);
    k_finalize<<<NCLS, 256, 0, stream>>>(cls_sums, cur, total, out, N);
}